// Round 14
// baseline (85.318 us; speedup 1.0000x reference)
//
#include <hip/hip_runtime.h>
#include <hip/hip_bf16.h>

#define HID 256
#define ADDF 7
#define MLP1 128
#define BN_EPS 1e-5f
#define NREP 8               // T/T2 atomic replicas

// ---- binning: 1024 bins x 98 nodes, atomic-free counting sort ----
#define NB 1024
#define BW 98                // NB*BW = 100352 >= N
#define BCAP 2048            // mean 1562 edges/bin, +12 sigma
#define NW 4                 // per-wave histogram replicas (hist kernel, 256 thr)
#define NR 8                 // LDS replicas in degv/agg (per 128-thread group)
#define NCHUNK 512           // edge chunks == 2 blocks/CU on hist/store
#define GQ 25                // gelu nodes per quarter-group (4*25 >= 98)

// tanh-form gelu: z*u/(u+1), u = exp(z*(2c0 + 2c0c1 z^2))
__device__ __forceinline__ float gelu_fast(float z) {
    float z2 = z * z;
    float y2 = z * fmaf(0.07135481627f, z2, 1.59576912161f);
    float u  = __expf(fminf(y2, 80.0f));
    return z * u * __builtin_amdgcn_rcpf(u + 1.0f);
}

// ---------------- 1: per-chunk histogram (+ zero accumulators) ----------------
__global__ __launch_bounds__(256) void k_hist(
        const int* __restrict__ dst, int* __restrict__ hist,
        float* __restrict__ zbase, int zcount, int E, int nchunk, int cpx, int PC) {
    __shared__ int h[NW][NB];
    const int t = threadIdx.x;
    const int bid = blockIdx.x;

    for (int gt = bid * 256 + t; gt < zcount; gt += (int)gridDim.x * 256) zbase[gt] = 0.0f;

    const int m = (bid & 7) * cpx + (bid >> 3);   // XCD-contiguous chunk id
    for (int k = t; k < NW * NB; k += 256) (&h[0][0])[k] = 0;
    __syncthreads();

    if (m < nchunk) {
        const int s0 = m * PC;
        const int e0 = min(s0 + PC, E);
        const int w = t >> 6;
        const bool al = ((((uintptr_t)(dst + s0)) & 15) == 0);
        const int n4 = al ? ((e0 - s0) >> 2) : 0;
        const int4* dst4 = (const int4*)(dst + s0);
        for (int q = t; q < n4; q += 256) {
            int4 d = dst4[q];
            atomicAdd(&h[w][d.x / BW], 1);
            atomicAdd(&h[w][d.y / BW], 1);
            atomicAdd(&h[w][d.z / BW], 1);
            atomicAdd(&h[w][d.w / BW], 1);
        }
        for (int i = s0 + (n4 << 2) + t; i < e0; i += 256)
            atomicAdd(&h[w][dst[i] / BW], 1);
        __syncthreads();
        for (int b = t; b < NB; b += 256)
            hist[(size_t)m * NB + b] = h[0][b] + h[1][b] + h[2][b] + h[3][b];
    }
}

// ---------------- 2: per-bin exclusive scan of hist columns (+ graph counts) ----------------
__global__ __launch_bounds__(64) void k_scan(
        int* __restrict__ hist, int* __restrict__ binCur,
        const int* __restrict__ batch, int* __restrict__ cnt,
        int nchunk, int N, int G) {
    const int bin = blockIdx.x;
    const int lane = threadIdx.x;
    __shared__ int bounds[2];

    if (bin < G && lane < 2) {
        int target = bin + lane;
        int lo = 0, hi = N;
        while (lo < hi) { int mid = (lo + hi) >> 1; if (batch[mid] < target) lo = mid + 1; else hi = mid; }
        bounds[lane] = lo;
    }

    const int per = (nchunk + 63) / 64;
    const int m0 = lane * per;
    const int m1 = min(m0 + per, nchunk);
    int sum = 0;
    for (int m = m0; m < m1; ++m) sum += hist[(size_t)m * NB + bin];

    int incl = sum;
    #pragma unroll
    for (int d = 1; d < 64; d <<= 1) {
        int o = __shfl_up(incl, d);
        if (lane >= d) incl += o;
    }
    const int total = __shfl(incl, 63);
    int run = bin * BCAP + (incl - sum);
    for (int m = m0; m < m1; ++m) {
        int c = hist[(size_t)m * NB + bin];
        hist[(size_t)m * NB + bin] = run;
        run += c;
    }
    if (lane == 63) binCur[bin] = bin * BCAP + total;

    __syncthreads();
    if (bin < G && lane == 0) cnt[bin] = bounds[1] - bounds[0];
}

// ---------------- 3: store records at scanned positions (no global atomics) ----------------
__global__ __launch_bounds__(256) void k_store(
        const int* __restrict__ src, const int* __restrict__ dst,
        const int* __restrict__ hist, int* __restrict__ recs,
        int E, int nchunk, int cpx, int PC) {
    __shared__ int cur[NB];
    const int t = threadIdx.x;
    const int m = ((int)blockIdx.x & 7) * cpx + ((int)blockIdx.x >> 3);
    if (m >= nchunk) return;

    {
        const int4* hrow = (const int4*)(hist + (size_t)m * NB);
        int4* cur4 = (int4*)cur;
        for (int b = t; b < NB / 4; b += 256) cur4[b] = hrow[b];
    }
    __syncthreads();

    const int s0 = m * PC;
    const int e0 = min(s0 + PC, E);
    const bool al = (((((uintptr_t)(dst + s0)) | ((uintptr_t)(src + s0))) & 15) == 0);
    const int n4 = al ? ((e0 - s0) >> 2) : 0;
    const int4* dst4 = (const int4*)(dst + s0);
    const int4* src4 = (const int4*)(src + s0);
    for (int q = t; q < n4; q += 256) {
        int4 d = dst4[q];
        int4 s = src4[q];
        int bin, pos;
        bin = d.x / BW; pos = atomicAdd(&cur[bin], 1); recs[pos] = ((d.x - bin * BW) << 17) | s.x;
        bin = d.y / BW; pos = atomicAdd(&cur[bin], 1); recs[pos] = ((d.y - bin * BW) << 17) | s.y;
        bin = d.z / BW; pos = atomicAdd(&cur[bin], 1); recs[pos] = ((d.z - bin * BW) << 17) | s.z;
        bin = d.w / BW; pos = atomicAdd(&cur[bin], 1); recs[pos] = ((d.w - bin * BW) << 17) | s.w;
    }
    for (int i = s0 + (n4 << 2) + t; i < e0; i += 256) {
        int d = dst[i];
        int bin = d / BW;
        int pos = atomicAdd(&cur[bin], 1);
        recs[pos] = ((d - bin * BW) << 17) | src[i];
    }
}

// ---------------- 4: per-bin degree -> dinv, v = x*dinv (x8 replicated, 1024 thr) ----------------
__global__ __launch_bounds__(1024) void k_degv(
        const int* __restrict__ recs, const int* __restrict__ binCur,
        const float* __restrict__ x, float* __restrict__ dinv, float* __restrict__ v, int N) {
    __shared__ int degL[NR][BW];
    const int b = blockIdx.x;
    const int t = threadIdx.x;
    const int rp = t >> 7;
    for (int k = t; k < NR * BW; k += 1024) (&degL[0][0])[k] = 0;
    __syncthreads();

    const int start = b * BCAP;
    const int end   = binCur[b];
    const int n4 = (end - start) >> 2;
    const int4* r4 = (const int4*)(recs + start);
    for (int q = t; q < n4; q += 1024) {
        int4 r = r4[q];
        atomicAdd(&degL[rp][r.x >> 17], 1);
        atomicAdd(&degL[rp][r.y >> 17], 1);
        atomicAdd(&degL[rp][r.z >> 17], 1);
        atomicAdd(&degL[rp][r.w >> 17], 1);
    }
    for (int i = start + (n4 << 2) + t; i < end; i += 1024)
        atomicAdd(&degL[rp][recs[i] >> 17], 1);
    __syncthreads();

    int node = b * BW + t;
    if (t < BW && node < N) {
        int d = 0;
        #pragma unroll
        for (int r = 0; r < NR; ++r) d += degL[r][t];
        float di = rsqrtf((float)d + 1.0f);   // +1 self-loop
        dinv[node] = di;
        v[node]    = di * x[node];
    }
}

// ---------------- 5: fused per-bin agg -> s -> gelu accumulate (1024 thr, 4-way) ----------------
__global__ __launch_bounds__(1024) void k_agg_gelu(
        const int* __restrict__ recs, const int* __restrict__ binCur,
        const float* __restrict__ v, const float* __restrict__ dinv,
        const int* __restrict__ batch,
        const float* __restrict__ Wc, const float* __restrict__ bc,
        float* __restrict__ Sgj, float* __restrict__ Trep, float* __restrict__ T2rep, int N) {
    __shared__ float aggL[NR][BW];
    __shared__ float sh_s[BW];
    __shared__ int   sh_b[BW];
    const int b = blockIdx.x;
    const int t = threadIdx.x;
    const int rp = t >> 7;
    for (int k = t; k < NR * BW; k += 1024) (&aggL[0][0])[k] = 0.0f;
    __syncthreads();

    const int start = b * BCAP;
    const int end   = binCur[b];
    const int n4 = (end - start) >> 2;
    const int4* r4 = (const int4*)(recs + start);
    for (int q = t; q < n4; q += 1024) {
        int4 r = r4[q];
        atomicAdd(&aggL[rp][r.x >> 17], v[r.x & 0x1FFFF]);
        atomicAdd(&aggL[rp][r.y >> 17], v[r.y & 0x1FFFF]);
        atomicAdd(&aggL[rp][r.z >> 17], v[r.z & 0x1FFFF]);
        atomicAdd(&aggL[rp][r.w >> 17], v[r.w & 0x1FFFF]);
    }
    for (int i = start + (n4 << 2) + t; i < end; i += 1024) {
        int rec = recs[i];
        atomicAdd(&aggL[rp][rec >> 17], v[rec & 0x1FFFF]);
    }
    __syncthreads();

    const int node0 = b * BW;
    const int count = min(BW, N - node0);
    if (count <= 0) return;

    if (t < count) {
        int node = node0 + t;
        float a = 0.f;
        #pragma unroll
        for (int r = 0; r < NR; ++r) a += aggL[r][t];
        sh_s[t] = dinv[node] * (a + v[node]);   // s = dinv*(agg + x*dinv)
        sh_b[t] = batch[node];
    }
    __syncthreads();

    // four 256-thread groups each handle a GQ-node slice, all 256 features
    const int f = t & 255;
    const int qg = t >> 8;
    const int nbeg = qg * GQ;
    const int nend = min(nbeg + GQ, count);
    if (nbeg < nend) {
        const float wa = Wc[f];
        const float wb = bc[f];
        float tsum = 0.f, t2sum = 0.f, gsum = 0.f;
        int gid = sh_b[nbeg];
        int n = nbeg;
        for (; n + 2 <= nend; n += 2) {
            float h0 = gelu_fast(fmaf(sh_s[n],     wa, wb));
            float h1 = gelu_fast(fmaf(sh_s[n + 1], wa, wb));
            int b0 = sh_b[n], b1v = sh_b[n + 1];
            tsum += h0 + h1; t2sum += fmaf(h0, h0, h1 * h1);
            if (b0 != gid)  { atomicAdd(&Sgj[gid * HID + f], gsum); gsum = 0.f; gid = b0; }
            gsum += h0;
            if (b1v != gid) { atomicAdd(&Sgj[gid * HID + f], gsum); gsum = 0.f; gid = b1v; }
            gsum += h1;
        }
        if (n < nend) {
            float h0 = gelu_fast(fmaf(sh_s[n], wa, wb));
            tsum += h0; t2sum += h0 * h0;
            int b0 = sh_b[n];
            if (b0 != gid) { atomicAdd(&Sgj[gid * HID + f], gsum); gsum = 0.f; gid = b0; }
            gsum += h0;
        }
        atomicAdd(&Sgj[gid * HID + f], gsum);
        const int r = ((int)b * 4 + qg) & (NREP - 1);
        atomicAdd(&Trep [r * HID + f], tsum);
        atomicAdd(&T2rep[r * HID + f], t2sum);
    }
}

// ---------------- 6: fused pool + BN + MLP ----------------
__global__ __launch_bounds__(HID) void k_pool_mlp(
        const float* __restrict__ Sgj, const float* __restrict__ Trep, const float* __restrict__ T2rep,
        const int* __restrict__ cnt, const float* __restrict__ gamma, const float* __restrict__ beta,
        const float* __restrict__ yfeat,
        const float* __restrict__ W1, const float* __restrict__ b1,
        const float* __restrict__ W2, const float* __restrict__ b2,
        float* __restrict__ out, int N) {
    __shared__ float gv[HID + ADDF];
    __shared__ float hid[MLP1];
    const int g = blockIdx.x;
    const int t = threadIdx.x;

    float Ts = 0.f, T2s = 0.f;
    #pragma unroll
    for (int r = 0; r < NREP; ++r) { Ts += Trep[r * HID + t]; T2s += T2rep[r * HID + t]; }
    float invN = 1.0f / (float)N;
    float mean = Ts * invN;
    float var  = fmaf(-mean, mean, T2s * invN);
    float rinv = rsqrtf(var + BN_EPS);
    float c = (float)max(cnt[g], 1);
    gv[t] = (Sgj[g * HID + t] / c - mean) * rinv * gamma[t] + beta[t];
    if (t < ADDF) gv[HID + t] = yfeat[g * ADDF + t];
    __syncthreads();

    if (t < MLP1) {
        float acc = b1[t];
        #pragma unroll 8
        for (int k = 0; k < HID + ADDF; ++k)
            acc = fmaf(gv[k], W1[k * MLP1 + t], acc);
        hid[t] = gelu_fast(acc);
    }
    __syncthreads();

    if (t < 2) {
        float o = b2[t];
        for (int k = 0; k < MLP1; ++k)
            o = fmaf(hid[k], W2[k * 2 + t], o);
        out[g * 2 + t] = 1.0f / (1.0f + expf(-o));
    }
}

// ================= fallback (global-atomic) kernels =================
__global__ void k_init_fb(float* zp, int nz, const int* __restrict__ batch,
                          int* __restrict__ cnt, int N, int G) {
    const int nzBlocks = (nz + 255) / 256;
    if ((int)blockIdx.x < nzBlocks) {
        int i = blockIdx.x * 256 + threadIdx.x;
        if (i < nz) zp[i] = 0.0f;
    } else {
        const int t = threadIdx.x;
        if (t < G) {
            int lo = 0, hi = N;
            while (lo < hi) { int mid = (lo + hi) >> 1; if (batch[mid] < t) lo = mid + 1; else hi = mid; }
            int start = lo;
            lo = 0; hi = N;
            while (lo < hi) { int mid = (lo + hi) >> 1; if (batch[mid] < t + 1) lo = mid + 1; else hi = mid; }
            cnt[t] = lo - start;
        }
    }
}
__global__ void k_zero(float* p, int n) {
    for (int i = blockIdx.x * blockDim.x + threadIdx.x; i < n; i += gridDim.x * blockDim.x)
        p[i] = 0.0f;
}
__global__ void k_deg_fb(const int* __restrict__ dst, float* __restrict__ deg, int E) {
    int i = blockIdx.x * blockDim.x + threadIdx.x;
    if (i < E) atomicAdd(&deg[dst[i]], 1.0f);
}
__global__ void k_dinv_fb(float* __restrict__ deg, const float* __restrict__ x,
                          float* __restrict__ v, int N) {
    int i = blockIdx.x * blockDim.x + threadIdx.x;
    if (i < N) { float di = rsqrtf(deg[i] + 1.0f); deg[i] = di; v[i] = di * x[i]; }
}
__global__ void k_scatter_fb(const int* __restrict__ src, const int* __restrict__ dst,
                             const float* __restrict__ v, float* __restrict__ agg, int E) {
    int i = blockIdx.x * blockDim.x + threadIdx.x;
    if (i < E) atomicAdd(&agg[dst[i]], v[src[i]]);
}
#define CHUNK_FB 64
__global__ __launch_bounds__(HID) void k_gelu_fb(
        const float* __restrict__ v, const float* __restrict__ dinv,
        const float* __restrict__ agg, const int* __restrict__ batch,
        const float* __restrict__ Wc, const float* __restrict__ bc,
        float* __restrict__ Sgj, float* __restrict__ Trep, float* __restrict__ T2rep, int N) {
    __shared__ float sh_s[CHUNK_FB];
    __shared__ int   sh_b[CHUNK_FB];
    const int j = threadIdx.x;
    const int base = blockIdx.x * CHUNK_FB;
    const int count = min(CHUNK_FB, N - base);
    if (j < count) {
        int i = base + j;
        sh_s[j] = dinv[i] * (agg[i] + v[i]);
        sh_b[j] = batch[i];
    }
    __syncthreads();
    const float a = Wc[j];
    const float b = bc[j];
    float tsum = 0.f, t2sum = 0.f, gsum = 0.f;
    int gid = sh_b[0];
    for (int n = 0; n < count; ++n) {
        float h = gelu_fast(fmaf(sh_s[n], a, b));
        tsum += h; t2sum += h * h;
        int bg = sh_b[n];
        if (bg != gid) { atomicAdd(&Sgj[gid * HID + j], gsum); gsum = 0.f; gid = bg; }
        gsum += h;
    }
    atomicAdd(&Sgj[gid * HID + j], gsum);
    const int r = blockIdx.x & (NREP - 1);
    atomicAdd(&Trep [r * HID + j], tsum);
    atomicAdd(&T2rep[r * HID + j], t2sum);
}

extern "C" void kernel_launch(void* const* d_in, const int* in_sizes, int n_in,
                              void* d_out, int out_size, void* d_ws, size_t ws_size,
                              hipStream_t stream) {
    const float* x     = (const float*)d_in[0];
    const int*   edge  = (const int*)  d_in[1];
    const int*   batch = (const int*)  d_in[2];
    const float* yfeat = (const float*)d_in[3];
    const float* Wc    = (const float*)d_in[4];
    const float* bc    = (const float*)d_in[5];
    const float* gamma = (const float*)d_in[6];
    const float* beta  = (const float*)d_in[7];
    const float* W1    = (const float*)d_in[8];
    const float* b1    = (const float*)d_in[9];
    const float* W2    = (const float*)d_in[10];
    const float* b2    = (const float*)d_in[11];
    float* out = (float*)d_out;

    const int N = in_sizes[0];          // 100000
    const int E = in_sizes[1] / 2;      // 1600000
    const int G = in_sizes[3] / ADDF;   // 256

    const int* srcIdx = edge;
    const int* dstIdx = edge + E;

    // PC chosen so nchunk == NCHUNK (512) -> exactly 2 blocks/CU on edge passes
    const int PC     = (((E + NCHUNK - 1) / NCHUNK) + 3) & ~3;
    const int nchunk = (E + PC - 1) / PC;            // <= 512
    const int cpx    = (NCHUNK + 7) / 8;             // 64 chunks per XCD

    // ---- workspace layout ----
    float* ws     = (float*)d_ws;
    float* Sgj    = ws;                              // [G*HID]    zeroed in k_hist
    float* Trep   = Sgj + (size_t)G * HID;           // [NREP*HID]
    float* T2rep  = Trep + NREP * HID;               // [NREP*HID]
    int*   cnt    = (int*)(T2rep + NREP * HID);      // [G]
    int*   binCur = cnt + G;                         // [NB]
    float* dinv   = (float*)(binCur + NB);           // [NB*BW]
    float* v      = dinv + (size_t)NB * BW;          // [NB*BW]
    int*   hist   = (int*)(v + (size_t)NB * BW);     // [NCHUNK*NB]
    int*   recs   = hist + (size_t)NCHUNK * NB;      // [NB*BCAP]

    const size_t headF  = (size_t)G * HID + 2 * NREP * HID + G + NB + 2 * (size_t)NB * BW;
    const size_t needT1 = (headF + (size_t)NCHUNK * NB + (size_t)NB * BCAP) * 4;
    const int zeroCount = G * HID + 2 * NREP * HID;

    if (ws_size >= needT1 && N <= NB * BW && G <= NB && N < (1 << 17)) {
        // ---- atomic-free counting-sort path: 6 launches ----
        k_hist<<<NCHUNK, 256, 0, stream>>>(dstIdx, hist, Sgj, zeroCount, E, nchunk, cpx, PC);
        k_scan<<<NB, 64, 0, stream>>>(hist, binCur, batch, cnt, nchunk, N, G);
        k_store<<<NCHUNK, 256, 0, stream>>>(srcIdx, dstIdx, hist, recs, E, nchunk, cpx, PC);
        k_degv<<<NB, 1024, 0, stream>>>(recs, binCur, x, dinv, v, N);
        k_agg_gelu<<<NB, 1024, 0, stream>>>(recs, binCur, v, dinv, batch, Wc, bc, Sgj, Trep, T2rep, N);
        k_pool_mlp<<<G, HID, 0, stream>>>(Sgj, Trep, T2rep, cnt, gamma, beta, yfeat, W1, b1, W2, b2, out, N);
    } else {
        // ---- fallback: global-atomic path (generic N) ----
        float* degA = (float*)(binCur + NB);
        float* vA   = degA + N;
        float* aggA = vA + N;
        const int initBlocks = (zeroCount + 255) / 256 + 1;
        k_init_fb<<<initBlocks, 256, 0, stream>>>(Sgj, zeroCount, batch, cnt, N, G);
        k_zero<<<512, 256, 0, stream>>>(degA, N);
        k_zero<<<512, 256, 0, stream>>>(aggA, N);
        k_deg_fb<<<(E + 255) / 256, 256, 0, stream>>>(dstIdx, degA, E);
        k_dinv_fb<<<(N + 255) / 256, 256, 0, stream>>>(degA, x, vA, N);
        k_scatter_fb<<<(E + 255) / 256, 256, 0, stream>>>(srcIdx, dstIdx, vA, aggA, E);
        k_gelu_fb<<<(N + CHUNK_FB - 1) / CHUNK_FB, HID, 0, stream>>>(vA, degA, aggA, batch, Wc, bc, Sgj, Trep, T2rep, N);
        k_pool_mlp<<<G, HID, 0, stream>>>(Sgj, Trep, T2rep, cnt, gamma, beta, yfeat, W1, b1, W2, b2, out, N);
    }
}

// Round 15
// 72.406 us; speedup vs baseline: 1.1783x; 1.1783x over previous
//
#include <hip/hip_runtime.h>
#include <hip/hip_bf16.h>

#define HID 256
#define ADDF 7
#define MLP1 128
#define BN_EPS 1e-5f
#define NREP 8               // T/T2 atomic replicas

// ---- binning: 512 bins x 196 nodes, atomic-free counting sort (r11 config) ----
#define NB 512
#define BW 196               // NB*BW = 100352 >= N
#define BCAP 4096            // mean 3125 edges/bin, +17 sigma
#define NW 16                // per-wave histogram replicas (hist kernel, 1024 thr)
#define NR 8                 // LDS replicas in degv/agg (per 128-thread group)
#define NCHUNK 512           // chunks == 2 blocks/CU exactly

// tanh-form gelu: z*u/(u+1), u = exp(z*(2c0 + 2c0c1 z^2))
__device__ __forceinline__ float gelu_fast(float z) {
    float z2 = z * z;
    float y2 = z * fmaf(0.07135481627f, z2, 1.59576912161f);
    float u  = __expf(fminf(y2, 80.0f));
    return z * u * __builtin_amdgcn_rcpf(u + 1.0f);
}

// ---------------- 1: per-chunk histogram, 1024 thr (+ zero accumulators) ----------------
__global__ __launch_bounds__(1024) void k_hist(
        const int* __restrict__ dst, int* __restrict__ hist,
        float* __restrict__ zbase, int zcount, int E, int nchunk, int cpx, int PC) {
    __shared__ int h[NW][NB];               // 32 KB
    const int t = threadIdx.x;
    const int bid = blockIdx.x;

    // fold: zero Sgj/Trep/T2rep (consumed 4 launches later)
    for (int gt = bid * 1024 + t; gt < zcount; gt += (int)gridDim.x * 1024) zbase[gt] = 0.0f;

    const int m = (bid & 7) * cpx + (bid >> 3);   // XCD-contiguous chunk id
    for (int k = t; k < NW * NB; k += 1024) (&h[0][0])[k] = 0;
    __syncthreads();

    if (m < nchunk) {
        const int s0 = m * PC;
        const int e0 = min(s0 + PC, E);
        const int w = t >> 6;
        const bool al = ((((uintptr_t)(dst + s0)) & 15) == 0);
        const int n4 = al ? ((e0 - s0) >> 2) : 0;
        const int4* dst4 = (const int4*)(dst + s0);
        for (int q = t; q < n4; q += 1024) {
            int4 d = dst4[q];
            atomicAdd(&h[w][d.x / BW], 1);
            atomicAdd(&h[w][d.y / BW], 1);
            atomicAdd(&h[w][d.z / BW], 1);
            atomicAdd(&h[w][d.w / BW], 1);
        }
        for (int i = s0 + (n4 << 2) + t; i < e0; i += 1024)
            atomicAdd(&h[w][dst[i] / BW], 1);
        __syncthreads();
        for (int b = t; b < NB; b += 1024) {
            int s = 0;
            #pragma unroll
            for (int ww = 0; ww < NW; ++ww) s += h[ww][b];
            hist[(size_t)m * NB + b] = s;
        }
    }
}

// ---------------- 2: per-bin exclusive scan of hist columns (+ graph counts) ----------------
__global__ __launch_bounds__(64) void k_scan(
        int* __restrict__ hist, int* __restrict__ binCur,
        const int* __restrict__ batch, int* __restrict__ cnt,
        int nchunk, int N, int G) {
    const int bin = blockIdx.x;
    const int lane = threadIdx.x;
    __shared__ int bounds[2];

    // graph counts on lanes 0/1 of blocks < G (parallel with scan)
    if (bin < G && lane < 2) {
        int target = bin + lane;
        int lo = 0, hi = N;
        while (lo < hi) { int mid = (lo + hi) >> 1; if (batch[mid] < target) lo = mid + 1; else hi = mid; }
        bounds[lane] = lo;
    }

    const int per = (nchunk + 63) / 64;
    const int m0 = lane * per;
    const int m1 = min(m0 + per, nchunk);
    int sum = 0;
    for (int m = m0; m < m1; ++m) sum += hist[(size_t)m * NB + bin];

    // wave inclusive scan of per-lane sums
    int incl = sum;
    #pragma unroll
    for (int d = 1; d < 64; d <<= 1) {
        int o = __shfl_up(incl, d);
        if (lane >= d) incl += o;
    }
    const int total = __shfl(incl, 63);
    int run = bin * BCAP + (incl - sum);          // exclusive base for this lane's chunks
    for (int m = m0; m < m1; ++m) {
        int c = hist[(size_t)m * NB + bin];
        hist[(size_t)m * NB + bin] = run;
        run += c;
    }
    if (lane == 63) binCur[bin] = bin * BCAP + total;

    __syncthreads();
    if (bin < G && lane == 0) cnt[bin] = bounds[1] - bounds[0];
}

// ---------------- 3: store records at scanned positions, 1024 thr ----------------
__global__ __launch_bounds__(1024) void k_store(
        const int* __restrict__ src, const int* __restrict__ dst,
        const int* __restrict__ hist, int* __restrict__ recs,
        int E, int nchunk, int cpx, int PC) {
    __shared__ int cur[NB];
    const int t = threadIdx.x;
    const int m = ((int)blockIdx.x & 7) * cpx + ((int)blockIdx.x >> 3);
    if (m >= nchunk) return;

    {   // seed cursors (vectorized)
        const int4* hrow = (const int4*)(hist + (size_t)m * NB);
        int4* cur4 = (int4*)cur;
        if (t < NB / 4) cur4[t] = hrow[t];
    }
    __syncthreads();

    const int s0 = m * PC;
    const int e0 = min(s0 + PC, E);
    const bool al = (((((uintptr_t)(dst + s0)) | ((uintptr_t)(src + s0))) & 15) == 0);
    const int n4 = al ? ((e0 - s0) >> 2) : 0;
    const int4* dst4 = (const int4*)(dst + s0);
    const int4* src4 = (const int4*)(src + s0);
    for (int q = t; q < n4; q += 1024) {
        int4 d = dst4[q];
        int4 s = src4[q];
        int bin, pos;
        bin = d.x / BW; pos = atomicAdd(&cur[bin], 1); recs[pos] = ((d.x - bin * BW) << 17) | s.x;
        bin = d.y / BW; pos = atomicAdd(&cur[bin], 1); recs[pos] = ((d.y - bin * BW) << 17) | s.y;
        bin = d.z / BW; pos = atomicAdd(&cur[bin], 1); recs[pos] = ((d.z - bin * BW) << 17) | s.z;
        bin = d.w / BW; pos = atomicAdd(&cur[bin], 1); recs[pos] = ((d.w - bin * BW) << 17) | s.w;
    }
    for (int i = s0 + (n4 << 2) + t; i < e0; i += 1024) {
        int d = dst[i];
        int bin = d / BW;
        int pos = atomicAdd(&cur[bin], 1);
        recs[pos] = ((d - bin * BW) << 17) | src[i];
    }
}

// ---------------- 4: per-bin degree -> dinv, v = x*dinv (x8 replicated, 1024 thr) ----------------
__global__ __launch_bounds__(1024) void k_degv(
        const int* __restrict__ recs, const int* __restrict__ binCur,
        const float* __restrict__ x, float* __restrict__ dinv, float* __restrict__ v, int N) {
    __shared__ int degL[NR][BW];
    const int b = blockIdx.x;
    const int t = threadIdx.x;
    const int rp = t >> 7;                 // 128-thread replica group
    for (int k = t; k < NR * BW; k += 1024) (&degL[0][0])[k] = 0;
    __syncthreads();

    const int start = b * BCAP;
    const int end   = binCur[b];
    const int n4 = (end - start) >> 2;
    const int4* r4 = (const int4*)(recs + start);
    for (int q = t; q < n4; q += 1024) {
        int4 r = r4[q];
        atomicAdd(&degL[rp][r.x >> 17], 1);
        atomicAdd(&degL[rp][r.y >> 17], 1);
        atomicAdd(&degL[rp][r.z >> 17], 1);
        atomicAdd(&degL[rp][r.w >> 17], 1);
    }
    for (int i = start + (n4 << 2) + t; i < end; i += 1024)
        atomicAdd(&degL[rp][recs[i] >> 17], 1);
    __syncthreads();

    int node = b * BW + t;
    if (t < BW && node < N) {
        int d = 0;
        #pragma unroll
        for (int r = 0; r < NR; ++r) d += degL[r][t];
        float di = rsqrtf((float)d + 1.0f);   // +1 self-loop
        dinv[node] = di;
        v[node]    = di * x[node];
    }
}

// ---------------- 5: fused per-bin agg -> s -> gelu accumulate (1024 thr, 4-way) ----------------
__global__ __launch_bounds__(1024) void k_agg_gelu(
        const int* __restrict__ recs, const int* __restrict__ binCur,
        const float* __restrict__ v, const float* __restrict__ dinv,
        const int* __restrict__ batch,
        const float* __restrict__ Wc, const float* __restrict__ bc,
        float* __restrict__ Sgj, float* __restrict__ Trep, float* __restrict__ T2rep, int N) {
    __shared__ float aggL[NR][BW];
    __shared__ float sh_s[BW];
    __shared__ int   sh_b[BW];
    const int b = blockIdx.x;
    const int t = threadIdx.x;
    const int rp = t >> 7;
    for (int k = t; k < NR * BW; k += 1024) (&aggL[0][0])[k] = 0.0f;
    __syncthreads();

    const int start = b * BCAP;
    const int end   = binCur[b];
    const int n4 = (end - start) >> 2;
    const int4* r4 = (const int4*)(recs + start);
    for (int q = t; q < n4; q += 1024) {
        int4 r = r4[q];
        atomicAdd(&aggL[rp][r.x >> 17], v[r.x & 0x1FFFF]);
        atomicAdd(&aggL[rp][r.y >> 17], v[r.y & 0x1FFFF]);
        atomicAdd(&aggL[rp][r.z >> 17], v[r.z & 0x1FFFF]);
        atomicAdd(&aggL[rp][r.w >> 17], v[r.w & 0x1FFFF]);
    }
    for (int i = start + (n4 << 2) + t; i < end; i += 1024) {
        int rec = recs[i];
        atomicAdd(&aggL[rp][rec >> 17], v[rec & 0x1FFFF]);
    }
    __syncthreads();

    const int node0 = b * BW;
    const int count = min(BW, N - node0);
    if (count <= 0) return;

    if (t < count) {
        int node = node0 + t;
        float a = 0.f;
        #pragma unroll
        for (int r = 0; r < NR; ++r) a += aggL[r][t];
        sh_s[t] = dinv[node] * (a + v[node]);   // s = dinv*(agg + x*dinv)
        sh_b[t] = batch[node];
    }
    __syncthreads();

    // four 256-thread groups each handle a 49-node quarter, all 256 features
    const int f = t & 255;
    const int qg = t >> 8;
    const int nbeg = qg * 49;
    const int nend = min(nbeg + 49, count);
    if (nbeg < nend) {
        const float wa = Wc[f];
        const float wb = bc[f];
        float tsum = 0.f, t2sum = 0.f, gsum = 0.f;
        int gid = sh_b[nbeg];
        int n = nbeg;
        for (; n + 2 <= nend; n += 2) {
            float h0 = gelu_fast(fmaf(sh_s[n],     wa, wb));
            float h1 = gelu_fast(fmaf(sh_s[n + 1], wa, wb));
            int b0 = sh_b[n], b1v = sh_b[n + 1];
            tsum += h0 + h1; t2sum += fmaf(h0, h0, h1 * h1);
            if (b0 != gid)  { atomicAdd(&Sgj[gid * HID + f], gsum); gsum = 0.f; gid = b0; }
            gsum += h0;
            if (b1v != gid) { atomicAdd(&Sgj[gid * HID + f], gsum); gsum = 0.f; gid = b1v; }
            gsum += h1;
        }
        if (n < nend) {
            float h0 = gelu_fast(fmaf(sh_s[n], wa, wb));
            tsum += h0; t2sum += h0 * h0;
            int b0 = sh_b[n];
            if (b0 != gid) { atomicAdd(&Sgj[gid * HID + f], gsum); gsum = 0.f; gid = b0; }
            gsum += h0;
        }
        atomicAdd(&Sgj[gid * HID + f], gsum);
        const int r = ((int)blockIdx.x * 4 + qg) & (NREP - 1);
        atomicAdd(&Trep [r * HID + f], tsum);
        atomicAdd(&T2rep[r * HID + f], t2sum);
    }
}

// ---------------- 6: fused pool + BN + MLP ----------------
__global__ __launch_bounds__(HID) void k_pool_mlp(
        const float* __restrict__ Sgj, const float* __restrict__ Trep, const float* __restrict__ T2rep,
        const int* __restrict__ cnt, const float* __restrict__ gamma, const float* __restrict__ beta,
        const float* __restrict__ yfeat,
        const float* __restrict__ W1, const float* __restrict__ b1,
        const float* __restrict__ W2, const float* __restrict__ b2,
        float* __restrict__ out, int N) {
    __shared__ float gv[HID + ADDF];
    __shared__ float hid[MLP1];
    const int g = blockIdx.x;
    const int t = threadIdx.x;

    float Ts = 0.f, T2s = 0.f;
    #pragma unroll
    for (int r = 0; r < NREP; ++r) { Ts += Trep[r * HID + t]; T2s += T2rep[r * HID + t]; }
    float invN = 1.0f / (float)N;
    float mean = Ts * invN;
    float var  = fmaf(-mean, mean, T2s * invN);
    float rinv = rsqrtf(var + BN_EPS);
    float c = (float)max(cnt[g], 1);
    gv[t] = (Sgj[g * HID + t] / c - mean) * rinv * gamma[t] + beta[t];
    if (t < ADDF) gv[HID + t] = yfeat[g * ADDF + t];
    __syncthreads();

    if (t < MLP1) {
        float acc = b1[t];
        #pragma unroll 8
        for (int k = 0; k < HID + ADDF; ++k)
            acc = fmaf(gv[k], W1[k * MLP1 + t], acc);
        hid[t] = gelu_fast(acc);
    }
    __syncthreads();

    if (t < 2) {
        float o = b2[t];
        for (int k = 0; k < MLP1; ++k)
            o = fmaf(hid[k], W2[k * 2 + t], o);
        out[g * 2 + t] = 1.0f / (1.0f + expf(-o));
    }
}

// ================= fallback (global-atomic) kernels =================
__global__ void k_init_fb(float* zp, int nz, const int* __restrict__ batch,
                          int* __restrict__ cnt, int N, int G) {
    const int nzBlocks = (nz + 255) / 256;
    if ((int)blockIdx.x < nzBlocks) {
        int i = blockIdx.x * 256 + threadIdx.x;
        if (i < nz) zp[i] = 0.0f;
    } else {
        const int t = threadIdx.x;
        if (t < G) {
            int lo = 0, hi = N;
            while (lo < hi) { int mid = (lo + hi) >> 1; if (batch[mid] < t) lo = mid + 1; else hi = mid; }
            int start = lo;
            lo = 0; hi = N;
            while (lo < hi) { int mid = (lo + hi) >> 1; if (batch[mid] < t + 1) lo = mid + 1; else hi = mid; }
            cnt[t] = lo - start;
        }
    }
}
__global__ void k_zero(float* p, int n) {
    for (int i = blockIdx.x * blockDim.x + threadIdx.x; i < n; i += gridDim.x * blockDim.x)
        p[i] = 0.0f;
}
__global__ void k_deg_fb(const int* __restrict__ dst, float* __restrict__ deg, int E) {
    int i = blockIdx.x * blockDim.x + threadIdx.x;
    if (i < E) atomicAdd(&deg[dst[i]], 1.0f);
}
__global__ void k_dinv_fb(float* __restrict__ deg, const float* __restrict__ x,
                          float* __restrict__ v, int N) {
    int i = blockIdx.x * blockDim.x + threadIdx.x;
    if (i < N) { float di = rsqrtf(deg[i] + 1.0f); deg[i] = di; v[i] = di * x[i]; }
}
__global__ void k_scatter_fb(const int* __restrict__ src, const int* __restrict__ dst,
                             const float* __restrict__ v, float* __restrict__ agg, int E) {
    int i = blockIdx.x * blockDim.x + threadIdx.x;
    if (i < E) atomicAdd(&agg[dst[i]], v[src[i]]);
}
#define CHUNK_FB 64
__global__ __launch_bounds__(HID) void k_gelu_fb(
        const float* __restrict__ v, const float* __restrict__ dinv,
        const float* __restrict__ agg, const int* __restrict__ batch,
        const float* __restrict__ Wc, const float* __restrict__ bc,
        float* __restrict__ Sgj, float* __restrict__ Trep, float* __restrict__ T2rep, int N) {
    __shared__ float sh_s[CHUNK_FB];
    __shared__ int   sh_b[CHUNK_FB];
    const int j = threadIdx.x;
    const int base = blockIdx.x * CHUNK_FB;
    const int count = min(CHUNK_FB, N - base);
    if (j < count) {
        int i = base + j;
        sh_s[j] = dinv[i] * (agg[i] + v[i]);
        sh_b[j] = batch[i];
    }
    __syncthreads();
    const float a = Wc[j];
    const float b = bc[j];
    float tsum = 0.f, t2sum = 0.f, gsum = 0.f;
    int gid = sh_b[0];
    for (int n = 0; n < count; ++n) {
        float h = gelu_fast(fmaf(sh_s[n], a, b));
        tsum += h; t2sum += h * h;
        int bg = sh_b[n];
        if (bg != gid) { atomicAdd(&Sgj[gid * HID + j], gsum); gsum = 0.f; gid = bg; }
        gsum += h;
    }
    atomicAdd(&Sgj[gid * HID + j], gsum);
    const int r = blockIdx.x & (NREP - 1);
    atomicAdd(&Trep [r * HID + j], tsum);
    atomicAdd(&T2rep[r * HID + j], t2sum);
}

extern "C" void kernel_launch(void* const* d_in, const int* in_sizes, int n_in,
                              void* d_out, int out_size, void* d_ws, size_t ws_size,
                              hipStream_t stream) {
    const float* x     = (const float*)d_in[0];
    const int*   edge  = (const int*)  d_in[1];
    const int*   batch = (const int*)  d_in[2];
    const float* yfeat = (const float*)d_in[3];
    const float* Wc    = (const float*)d_in[4];
    const float* bc    = (const float*)d_in[5];
    const float* gamma = (const float*)d_in[6];
    const float* beta  = (const float*)d_in[7];
    const float* W1    = (const float*)d_in[8];
    const float* b1    = (const float*)d_in[9];
    const float* W2    = (const float*)d_in[10];
    const float* b2    = (const float*)d_in[11];
    float* out = (float*)d_out;

    const int N = in_sizes[0];          // 100000
    const int E = in_sizes[1] / 2;      // 1600000
    const int G = in_sizes[3] / ADDF;   // 256

    const int* srcIdx = edge;
    const int* dstIdx = edge + E;

    // PC chosen so nchunk == NCHUNK (512) -> exactly 2 blocks/CU on edge passes
    const int PC     = (((E + NCHUNK - 1) / NCHUNK) + 3) & ~3;
    const int nchunk = (E + PC - 1) / PC;            // <= 512
    const int cpx    = (NCHUNK + 7) / 8;             // 64 chunks per XCD

    // ---- workspace layout ----
    float* ws     = (float*)d_ws;
    float* Sgj    = ws;                              // [G*HID]    zeroed in k_hist
    float* Trep   = Sgj + (size_t)G * HID;           // [NREP*HID]
    float* T2rep  = Trep + NREP * HID;               // [NREP*HID]
    int*   cnt    = (int*)(T2rep + NREP * HID);      // [G]
    int*   binCur = cnt + G;                         // [NB]
    float* dinv   = (float*)(binCur + NB);           // [NB*BW]
    float* v      = dinv + (size_t)NB * BW;          // [NB*BW]
    int*   hist   = (int*)(v + (size_t)NB * BW);     // [NCHUNK*NB]
    int*   recs   = hist + (size_t)NCHUNK * NB;      // [NB*BCAP]

    const size_t headF  = (size_t)G * HID + 2 * NREP * HID + G + NB + 2 * (size_t)NB * BW;
    const size_t needT1 = (headF + (size_t)NCHUNK * NB + (size_t)NB * BCAP) * 4;
    const int zeroCount = G * HID + 2 * NREP * HID;

    if (ws_size >= needT1 && N <= NB * BW && G <= NB && N < (1 << 17)) {
        // ---- atomic-free counting-sort path: 6 launches ----
        k_hist<<<NCHUNK, 1024, 0, stream>>>(dstIdx, hist, Sgj, zeroCount, E, nchunk, cpx, PC);
        k_scan<<<NB, 64, 0, stream>>>(hist, binCur, batch, cnt, nchunk, N, G);
        k_store<<<NCHUNK, 1024, 0, stream>>>(srcIdx, dstIdx, hist, recs, E, nchunk, cpx, PC);
        k_degv<<<NB, 1024, 0, stream>>>(recs, binCur, x, dinv, v, N);
        k_agg_gelu<<<NB, 1024, 0, stream>>>(recs, binCur, v, dinv, batch, Wc, bc, Sgj, Trep, T2rep, N);
        k_pool_mlp<<<G, HID, 0, stream>>>(Sgj, Trep, T2rep, cnt, gamma, beta, yfeat, W1, b1, W2, b2, out, N);
    } else {
        // ---- fallback: global-atomic path (generic N) ----
        float* degA = (float*)(binCur + NB);
        float* vA   = degA + N;
        float* aggA = vA + N;
        const int initBlocks = (zeroCount + 255) / 256 + 1;
        k_init_fb<<<initBlocks, 256, 0, stream>>>(Sgj, zeroCount, batch, cnt, N, G);
        k_zero<<<512, 256, 0, stream>>>(degA, N);
        k_zero<<<512, 256, 0, stream>>>(aggA, N);
        k_deg_fb<<<(E + 255) / 256, 256, 0, stream>>>(dstIdx, degA, E);
        k_dinv_fb<<<(N + 255) / 256, 256, 0, stream>>>(degA, x, vA, N);
        k_scatter_fb<<<(E + 255) / 256, 256, 0, stream>>>(srcIdx, dstIdx, vA, aggA, E);
        k_gelu_fb<<<(N + CHUNK_FB - 1) / CHUNK_FB, HID, 0, stream>>>(vA, degA, aggA, batch, Wc, bc, Sgj, Trep, T2rep, N);
        k_pool_mlp<<<G, HID, 0, stream>>>(Sgj, Trep, T2rep, cnt, gamma, beta, yfeat, W1, b1, W2, b2, out, N);
    }
}